// Round 18
// baseline (224.208 us; speedup 1.0000x reference)
//
#include <hip/hip_runtime.h>
#include <hip/hip_bf16.h>

typedef __attribute__((ext_vector_type(8))) short bf16x8;
typedef __attribute__((ext_vector_type(4))) float f32x4;
typedef __attribute__((ext_vector_type(8))) unsigned short u16x8;

#define WIDTH  2048
#define NHEADS 16
#define HDIM   128

__device__ __forceinline__ unsigned short f2bf(float f) {
  union { float f; unsigned int u; } v; v.f = f;
  unsigned int u = v.u;
  unsigned int r = (u + 0x7FFFu + ((u >> 16) & 1u)) >> 16;  // RNE
  return (unsigned short)r;
}

// pack two f32 -> two bf16 (RNE) via scalar-cast path (compiler emits cvt_pk)
__device__ __forceinline__ unsigned int pk_bf16(float lo, float hi) {
  __hip_bfloat162 b = __float22bfloat162_rn(make_float2(lo, hi));
  union { __hip_bfloat162 b; unsigned int u; } c; c.b = b;
  return c.u;
}

#define LOG2E 1.4426950408889634f

// Prep (coalesced, from R16/R17): blocks 0..63 transpose one 32-row slab of
// one head for BOTH weights via an LDS tile. Blocks 64..71: params.
__global__ __launch_bounds__(256) void prep_kernel(
    const float* __restrict__ w_in, const float* __restrict__ w_a,
    const float* __restrict__ a_param,
    const float* __restrict__ b_in, const float* __restrict__ b_a,
    unsigned short* __restrict__ wTin, unsigned short* __restrict__ wTa,
    float* __restrict__ sp8, float* __restrict__ sbi, float* __restrict__ sba) {
  const int b = blockIdx.x;
  if (b >= 64) {
    int tid = (b - 64) * 256 + threadIdx.x;   // 0..2047
    float v  = a_param[tid];
    float sp = (v > 20.0f) ? v : log1pf(__expf(v));
    sp8[tid] = 8.0f * sp * LOG2E;
    sbi[tid] = b_in[tid] * LOG2E;
    sba[tid] = b_a[tid] * LOG2E;
    return;
  }
  const int h  = b >> 2;
  const int i0 = (b & 3) * 32;                // input-dim slab
  __shared__ unsigned short tl[2][32][136];   // +8 pad

  const float* s0 = w_in + h * 16384 + i0 * 128;
  const float* s1 = w_a  + h * 16384 + i0 * 128;
#pragma unroll
  for (int it = 0; it < 4; ++it) {
    int e = it * 1024 + threadIdx.x * 4;      // 4 consecutive f32
    int r = e >> 7, c = e & 127;
    f32x4 v0 = *reinterpret_cast<const f32x4*>(s0 + r * 128 + c);
    f32x4 v1 = *reinterpret_cast<const f32x4*>(s1 + r * 128 + c);
#pragma unroll
    for (int k = 0; k < 4; ++k) {
      tl[0][r][c + k] = f2bf(v0[k] * LOG2E);
      tl[1][r][c + k] = f2bf(v1[k] * LOG2E);
    }
  }
  __syncthreads();

  const int j  = threadIdx.x >> 1;            // out col 0..127
  const int ih = (threadIdx.x & 1) * 16;      // i-half within slab
  u16x8 o0a, o0b, o1a, o1b;
#pragma unroll
  for (int k = 0; k < 8; ++k) {
    o0a[k] = tl[0][ih + k][j];      o0b[k] = tl[0][ih + 8 + k][j];
    o1a[k] = tl[1][ih + k][j];      o1b[k] = tl[1][ih + 8 + k][j];
  }
  unsigned short* d0 = wTin + h * 16384 + j * 128 + i0 + ih;
  unsigned short* d1 = wTa  + h * 16384 + j * 128 + i0 + ih;
  *reinterpret_cast<u16x8*>(d0)     = o0a;
  *reinterpret_cast<u16x8*>(d0 + 8) = o0b;
  *reinterpret_cast<u16x8*>(d1)     = o1a;
  *reinterpret_cast<u16x8*>(d1 + 8) = o1b;
}

// Barrier-free + temporally-compact: block shape/dispatch identical to R12
// (64 rows x 1 head, grid 4096) but each wave owns 16 rows x 128 cols with
// x loaded DIRECTLY into MFMA B-fragments. No LDS, no __syncthreads, no
// staging phase. Epilogue x via identity-MFMA transpose (verified R8-R10).
__global__ __launch_bounds__(256, 4) void rglru_kernel(
    const float* __restrict__ x, const float* __restrict__ state,
    const float* __restrict__ sbi, const float* __restrict__ sba,
    const unsigned short* __restrict__ wTin, const unsigned short* __restrict__ wTa,
    const float* __restrict__ sp8, float* __restrict__ out) {
  const int bid  = blockIdx.x;
  const int h    = bid & (NHEADS - 1);
  const int rb   = bid >> 4;
  const int t    = threadIdx.x;
  const int lane = t & 63;
  const int wid  = t >> 6;
  const int l15  = lane & 15;
  const int l4   = lane >> 4;

  const int  r0   = rb * 64 + wid * 16;            // wave's 16-row tile
  const long rowo = (long)(r0 + l15) * WIDTH + h * HDIM;

  // ---- x directly into B-fragments: row l15, cols kk*32 + l4*8 .. +8 ----
  const float* xrow = x + rowo + l4 * 8;
  f32x4 xq[4][2];
#pragma unroll
  for (int kk = 0; kk < 4; ++kk) {
    xq[kk][0] = *reinterpret_cast<const f32x4*>(xrow + kk * 32);
    xq[kk][1] = *reinterpret_cast<const f32x4*>(xrow + kk * 32 + 4);
  }
  bf16x8 xfr[4];
#pragma unroll
  for (int kk = 0; kk < 4; ++kk) {
    union { bf16x8 v; unsigned int u[4]; } uu;
    uu.u[0] = pk_bf16(xq[kk][0][0], xq[kk][0][1]);
    uu.u[1] = pk_bf16(xq[kk][0][2], xq[kk][0][3]);
    uu.u[2] = pk_bf16(xq[kk][1][0], xq[kk][1][1]);
    uu.u[3] = pk_bf16(xq[kk][1][2], xq[kk][1][3]);
    xfr[kk] = uu.v;
  }

  // ---- identity fragments for the in-register x transpose ----
  bf16x8 idf0, idf1;
  {
    union { bf16x8 v; unsigned short us[8]; } a0, a1;
#pragma unroll
    for (int e = 0; e < 8; ++e) {
      int k = l4 * 8 + e;
      a0.us[e] = (k == l15)      ? (unsigned short)0x3F80 : (unsigned short)0;
      a1.us[e] = (k == l15 + 16) ? (unsigned short)0x3F80 : (unsigned short)0;
    }
    idf0 = a0.v; idf1 = a1.v;
  }

  // ---- acc init with bias (C-in accumulates); n = 0..7 col groups ----
  const int cbase = h * HDIM + l4 * 4;
  f32x4 acc_in[8], acc_a[8];
#pragma unroll
  for (int n = 0; n < 8; ++n) {
    acc_in[n] = *reinterpret_cast<const f32x4*>(sbi + cbase + n * 16);
    acc_a[n]  = *reinterpret_cast<const f32x4*>(sba + cbase + n * 16);
  }

  // weight bases: [h][j][k] layout; lane j = n*16 + l15, k = kk*32 + l4*8
  const unsigned short* wb0 = wTin + (h * HDIM + l15) * HDIM + l4 * 8;
  const unsigned short* wb1 = wTa  + (h * HDIM + l15) * HDIM + l4 * 8;

  // ---- K-loop: outer kk, inner n (weights L1-hot, shared by 4 waves) ----
#pragma unroll
  for (int kk = 0; kk < 4; ++kk) {
    const unsigned short* w0 = wb0 + kk * 32;
    const unsigned short* w1 = wb1 + kk * 32;
#pragma unroll
    for (int n = 0; n < 8; ++n) {
      bf16x8 wi = *reinterpret_cast<const bf16x8*>(w0 + n * 16 * HDIM);
      bf16x8 wv = *reinterpret_cast<const bf16x8*>(w1 + n * 16 * HDIM);
      acc_in[n] = __builtin_amdgcn_mfma_f32_16x16x32_bf16(wi, xfr[kk], acc_in[n], 0, 0, 0);
      acc_a[n]  = __builtin_amdgcn_mfma_f32_16x16x32_bf16(wv, xfr[kk], acc_a[n], 0, 0, 0);
    }
  }

  // ---- epilogue: per col-group n, x recovered via identity MFMA ----
  const float* srow = state + rowo + l4 * 4;
  float*       orow = out + rowo + l4 * 4;
  const float* spb  = sp8 + cbase;
  const f32x4  zero = (f32x4)(0.0f);

#pragma unroll
  for (int n = 0; n < 8; ++n) {
    f32x4 sv = *reinterpret_cast<const f32x4*>(srow + n * 16);
    f32x4 sp = *reinterpret_cast<const f32x4*>(spb + n * 16);
    f32x4 xt = __builtin_amdgcn_mfma_f32_16x16x32_bf16(
        (n & 1) ? idf1 : idf0, xfr[n >> 1], zero, 0, 0, 0);
    f32x4 o;
#pragma unroll
    for (int r = 0; r < 4; ++r) {
      float gx = __builtin_amdgcn_rcpf(1.0f + exp2f(-acc_in[n][r]));
      float ga = __builtin_amdgcn_rcpf(1.0f + exp2f(-acc_a[n][r]));
      float av = exp2f(-ga * sp[r]);
      float sc = sqrtf(fmaxf(1.0f - av * av, 0.0f));
      o[r] = av * sv[r] + gx * xt[r] * sc;
    }
    *reinterpret_cast<f32x4*>(orow + n * 16) = o;
  }
}

extern "C" void kernel_launch(void* const* d_in, const int* in_sizes, int n_in,
                              void* d_out, int out_size, void* d_ws, size_t ws_size,
                              hipStream_t stream) {
  const float* x       = (const float*)d_in[0];
  const float* state   = (const float*)d_in[1];
  const float* w_in    = (const float*)d_in[2];
  const float* b_in    = (const float*)d_in[3];
  const float* w_a     = (const float*)d_in[4];
  const float* b_a     = (const float*)d_in[5];
  const float* a_param = (const float*)d_in[6];
  float* out = (float*)d_out;

  unsigned short* wTin = (unsigned short*)d_ws;
  unsigned short* wTa  = wTin + NHEADS * HDIM * HDIM;
  float*          sp8  = (float*)(wTa + NHEADS * HDIM * HDIM);
  float*          sbi  = sp8 + WIDTH;
  float*          sba  = sbi + WIDTH;

  // prep: 64 transpose blocks + 8 param blocks
  hipLaunchKernelGGL(prep_kernel, dim3(72), dim3(256), 0, stream,
                     w_in, w_a, a_param, b_in, b_a, wTin, wTa, sp8, sbi, sba);

  // main: 4096 blocks x 256 threads; block = 64 rows x 1 head (as R12),
  // but 4 independent barrier-free waves of 16 rows x 128 cols each.
  hipLaunchKernelGGL(rglru_kernel, dim3(4096), dim3(256), 0, stream,
                     x, state, sbi, sba, wTin, wTa, sp8, out);
}

// Round 19
// 132.239 us; speedup vs baseline: 1.6955x; 1.6955x over previous
//
#include <hip/hip_runtime.h>
#include <hip/hip_bf16.h>

typedef __attribute__((ext_vector_type(8))) short bf16x8;
typedef __attribute__((ext_vector_type(4))) float f32x4;
typedef __attribute__((ext_vector_type(4))) unsigned short u16x4;
typedef __attribute__((ext_vector_type(8))) unsigned short u16x8;

#define WIDTH  2048
#define NHEADS 16
#define HDIM   128
#define BM     64

__device__ __forceinline__ unsigned short f2bf(float f) {
  union { float f; unsigned int u; } v; v.f = f;
  unsigned int u = v.u;
  unsigned int r = (u + 0x7FFFu + ((u >> 16) & 1u)) >> 16;  // RNE
  return (unsigned short)r;
}

__device__ __forceinline__ float bf2f(unsigned short s) {
  union { unsigned int u; float f; } v;
  v.u = ((unsigned int)s) << 16;
  return v.f;
}

// pack two f32 -> two bf16 (RNE) via scalar-cast path (compiler emits cvt_pk)
__device__ __forceinline__ unsigned int pk_bf16(float lo, float hi) {
  __hip_bfloat162 b = __float22bfloat162_rn(make_float2(lo, hi));
  union { __hip_bfloat162 b; unsigned int u; } c; c.b = b;
  return c.u;
}

#define LOG2E 1.4426950408889634f

// Prep (coalesced, from R16/R17): blocks 0..63 transpose one 32-row slab of
// one head for BOTH weights via an LDS tile. Blocks 64..71: params.
__global__ __launch_bounds__(256) void prep_kernel(
    const float* __restrict__ w_in, const float* __restrict__ w_a,
    const float* __restrict__ a_param,
    const float* __restrict__ b_in, const float* __restrict__ b_a,
    unsigned short* __restrict__ wTin, unsigned short* __restrict__ wTa,
    float* __restrict__ sp8, float* __restrict__ sbi, float* __restrict__ sba) {
  const int b = blockIdx.x;
  if (b >= 64) {
    int tid = (b - 64) * 256 + threadIdx.x;   // 0..2047
    float v  = a_param[tid];
    float sp = (v > 20.0f) ? v : log1pf(__expf(v));
    sp8[tid] = 8.0f * sp * LOG2E;
    sbi[tid] = b_in[tid] * LOG2E;
    sba[tid] = b_a[tid] * LOG2E;
    return;
  }
  const int h  = b >> 2;
  const int i0 = (b & 3) * 32;                // input-dim slab
  __shared__ unsigned short tl[2][32][136];   // +8 pad

  const float* s0 = w_in + h * 16384 + i0 * 128;
  const float* s1 = w_a  + h * 16384 + i0 * 128;
#pragma unroll
  for (int it = 0; it < 4; ++it) {
    int e = it * 1024 + threadIdx.x * 4;      // 4 consecutive f32
    int r = e >> 7, c = e & 127;
    f32x4 v0 = *reinterpret_cast<const f32x4*>(s0 + r * 128 + c);
    f32x4 v1 = *reinterpret_cast<const f32x4*>(s1 + r * 128 + c);
#pragma unroll
    for (int k = 0; k < 4; ++k) {
      tl[0][r][c + k] = f2bf(v0[k] * LOG2E);
      tl[1][r][c + k] = f2bf(v1[k] * LOG2E);
    }
  }
  __syncthreads();

  const int j  = threadIdx.x >> 1;            // out col 0..127
  const int ih = (threadIdx.x & 1) * 16;      // i-half within slab
  u16x8 o0a, o0b, o1a, o1b;
#pragma unroll
  for (int k = 0; k < 8; ++k) {
    o0a[k] = tl[0][ih + k][j];      o0b[k] = tl[0][ih + 8 + k][j];
    o1a[k] = tl[1][ih + k][j];      o1b[k] = tl[1][ih + 8 + k][j];
  }
  unsigned short* d0 = wTin + h * 16384 + j * 128 + i0 + ih;
  unsigned short* d1 = wTa  + h * 16384 + j * 128 + i0 + ih;
  *reinterpret_cast<u16x8*>(d0)     = o0a;
  *reinterpret_cast<u16x8*>(d0 + 8) = o0b;
  *reinterpret_cast<u16x8*>(d1)     = o1a;
  *reinterpret_cast<u16x8*>(d1 + 8) = o1b;
}

// R12 structure, TPB=2 double-buffered pipeline: block = 128 rows x 1 head
// (two 64-row tiles). Tile 1's x-loads are issued into registers BEFORE
// tile 0's MFMA+epilogue and committed to LDS after -> HBM demand persists
// through the compute phase (anti-convoy). Everything else identical to R12.
__global__ __launch_bounds__(256, 4) void rglru_kernel(
    const float* __restrict__ x, const float* __restrict__ state,
    const float* __restrict__ sbi, const float* __restrict__ sba,
    const unsigned short* __restrict__ wTin, const unsigned short* __restrict__ wTa,
    const float* __restrict__ sp8, float* __restrict__ out) {
  __shared__ unsigned short xs[2][BM * HDIM];  // 2 x 16 KB, XOR-swizzled

  const int bid  = blockIdx.x;                 // 0..2047
  const int h    = bid & (NHEADS - 1);
  const int rbb  = bid >> 4;                   // 128-row supertile, 0..127
  const int t    = threadIdx.x;
  const int lane = t & 63;
  const int wid  = t >> 6;
  const int l15  = lane & 15;
  const int l4   = lane >> 4;

  const int r_  = t >> 5;    // stage: row (0..7 step within 8-row stripes)
  const int c4_ = t & 31;    // stage: float4 index within row

  const float* xt0 = x + (long)(rbb * 2 * BM) * WIDTH + h * HDIM;

  // ---- stage tile 0 directly into LDS buf 0 ----
#pragma unroll
  for (int it = 0; it < 8; ++it) {
    int r = it * 8 + r_;
    f32x4 v = __builtin_nontemporal_load(
        reinterpret_cast<const f32x4*>(xt0 + (long)r * WIDTH) + c4_);
    uint2 p;
    p.x = pk_bf16(v[0], v[1]);
    p.y = pk_bf16(v[2], v[3]);
    int off = (r * 256 + c4_ * 8) ^ ((r & 7) << 4);
    *reinterpret_cast<uint2*>(reinterpret_cast<char*>(xs[0]) + off) = p;
  }

  // per-column constants (bias folded into acc init)
  const int cb = h * HDIM + wid * 32 + l4 * 4;
  f32x4 bi0 = *reinterpret_cast<const f32x4*>(sbi + cb);
  f32x4 bi1 = *reinterpret_cast<const f32x4*>(sbi + cb + 16);
  f32x4 ba0 = *reinterpret_cast<const f32x4*>(sba + cb);
  f32x4 ba1 = *reinterpret_cast<const f32x4*>(sba + cb + 16);
  f32x4 sp0 = *reinterpret_cast<const f32x4*>(sp8 + cb);
  f32x4 sp1 = *reinterpret_cast<const f32x4*>(sp8 + cb + 16);

  // weight base pointers
  const unsigned short* wi0 = wTin + ((h * HDIM + wid * 32 + l15) * HDIM) + l4 * 8;
  const unsigned short* wi1 = wi0 + 16 * HDIM;
  const unsigned short* wa0 = wTa + ((h * HDIM + wid * 32 + l15) * HDIM) + l4 * 8;
  const unsigned short* wa1 = wa0 + 16 * HDIM;

  const int xsw = ((l15 & 7) << 4);   // per-thread swizzle bits (4..6)
  const int xe0 = (l15 * 256 + (wid * 32 + l4 * 4) * 2) ^ xsw;        // n=0
  const int xe1 = (l15 * 256 + (wid * 32 + 16 + l4 * 4) * 2) ^ xsw;   // n=1

  __syncthreads();

  // ---- issue tile 1's x loads (in flight across tile 0's compute) ----
  f32x4 xa[8];
  {
    const float* xt1 = xt0 + (long)BM * WIDTH;
#pragma unroll
    for (int it = 0; it < 8; ++it) {
      int r = it * 8 + r_;
      xa[it] = __builtin_nontemporal_load(
          reinterpret_cast<const f32x4*>(xt1 + (long)r * WIDTH) + c4_);
    }
  }

#pragma unroll
  for (int tile = 0; tile < 2; ++tile) {
    // ---- MFMA: acc[m][n] initialized with bias ----
    f32x4 acc_in[4][2], acc_a[4][2];
#pragma unroll
    for (int m = 0; m < 4; ++m) {
      acc_in[m][0] = bi0; acc_in[m][1] = bi1;
      acc_a[m][0]  = ba0; acc_a[m][1]  = ba1;
    }

    const char* pxs = reinterpret_cast<const char*>(xs[tile]);

#pragma unroll
    for (int kk = 0; kk < 4; ++kk) {
      bf16x8 xfr[4];
#pragma unroll
      for (int m = 0; m < 4; ++m) {
        int boff = ((m * 16 + l15) * 256 + kk * 64 + l4 * 16) ^ xsw;
        xfr[m] = *reinterpret_cast<const bf16x8*>(pxs + boff);
      }
      bf16x8 win[2], wa[2];
      win[0] = *reinterpret_cast<const bf16x8*>(wi0 + kk * 32);
      win[1] = *reinterpret_cast<const bf16x8*>(wi1 + kk * 32);
      wa[0]  = *reinterpret_cast<const bf16x8*>(wa0 + kk * 32);
      wa[1]  = *reinterpret_cast<const bf16x8*>(wa1 + kk * 32);
#pragma unroll
      for (int m = 0; m < 4; ++m)
#pragma unroll
        for (int n = 0; n < 2; ++n) {
          acc_in[m][n] = __builtin_amdgcn_mfma_f32_16x16x32_bf16(
              win[n], xfr[m], acc_in[m][n], 0, 0, 0);
          acc_a[m][n] = __builtin_amdgcn_mfma_f32_16x16x32_bf16(
              wa[n], xfr[m], acc_a[m][n], 0, 0, 0);
        }
    }

    // ---- epilogue for this tile ----
    const long base = (long)(rbb * 2 * BM + tile * BM + l15) * WIDTH + cb;
    const float* ps = state + base;
    float*       po = out + base;

#pragma unroll
    for (int m = 0; m < 4; ++m) {
#pragma unroll
      for (int n = 0; n < 2; ++n) {
        f32x4 sv = *reinterpret_cast<const f32x4*>(ps + n * 16);
        u16x4 xb = *reinterpret_cast<const u16x4*>(
            pxs + (n ? xe1 : xe0) + m * 4096);
        f32x4 sp = n ? sp1 : sp0;
        f32x4 o;
#pragma unroll
        for (int r = 0; r < 4; ++r) {
          float gx  = __builtin_amdgcn_rcpf(1.0f + exp2f(-acc_in[m][n][r]));
          float ga  = __builtin_amdgcn_rcpf(1.0f + exp2f(-acc_a[m][n][r]));
          float av  = exp2f(-ga * sp[r]);
          float sc  = sqrtf(fmaxf(1.0f - av * av, 0.0f));
          o[r] = av * sv[r] + gx * bf2f(xb[r]) * sc;
        }
        *reinterpret_cast<f32x4*>(po + n * 16) = o;
      }
      ps += 16 * WIDTH;
      po += 16 * WIDTH;
    }

    // ---- commit tile 1's x into buf 1, then barrier ----
    if (tile == 0) {
#pragma unroll
      for (int it = 0; it < 8; ++it) {
        int r = it * 8 + r_;
        uint2 p;
        p.x = pk_bf16(xa[it][0], xa[it][1]);
        p.y = pk_bf16(xa[it][2], xa[it][3]);
        int off = (r * 256 + c4_ * 8) ^ ((r & 7) << 4);
        *reinterpret_cast<uint2*>(reinterpret_cast<char*>(xs[1]) + off) = p;
      }
      __syncthreads();
    }
  }
}

extern "C" void kernel_launch(void* const* d_in, const int* in_sizes, int n_in,
                              void* d_out, int out_size, void* d_ws, size_t ws_size,
                              hipStream_t stream) {
  const float* x       = (const float*)d_in[0];
  const float* state   = (const float*)d_in[1];
  const float* w_in    = (const float*)d_in[2];
  const float* b_in    = (const float*)d_in[3];
  const float* w_a     = (const float*)d_in[4];
  const float* b_a     = (const float*)d_in[5];
  const float* a_param = (const float*)d_in[6];
  float* out = (float*)d_out;

  unsigned short* wTin = (unsigned short*)d_ws;
  unsigned short* wTa  = wTin + NHEADS * HDIM * HDIM;
  float*          sp8  = (float*)(wTa + NHEADS * HDIM * HDIM);
  float*          sbi  = sp8 + WIDTH;
  float*          sba  = sbi + WIDTH;

  // prep: 64 transpose blocks + 8 param blocks
  hipLaunchKernelGGL(prep_kernel, dim3(72), dim3(256), 0, stream,
                     w_in, w_a, a_param, b_in, b_a, wTin, wTa, sp8, sbi, sba);

  // main: 2048 blocks x 256 threads; block = 128 rows x 1 head,
  // two 64-row tiles with a 2-deep x pipeline.
  hipLaunchKernelGGL(rglru_kernel, dim3(2048), dim3(256), 0, stream,
                     x, state, sbi, sba, wTin, wTa, sp8, out);
}

// Round 20
// 103.913 us; speedup vs baseline: 2.1577x; 1.2726x over previous
//
#include <hip/hip_runtime.h>
#include <hip/hip_bf16.h>

typedef __attribute__((ext_vector_type(8))) short bf16x8;
typedef __attribute__((ext_vector_type(4))) float f32x4;
typedef __attribute__((ext_vector_type(4))) unsigned short u16x4;
typedef __attribute__((ext_vector_type(8))) unsigned short u16x8;

#define WIDTH  2048
#define NHEADS 16
#define HDIM   128
#define BM     64

__device__ __forceinline__ unsigned short f2bf(float f) {
  union { float f; unsigned int u; } v; v.f = f;
  unsigned int u = v.u;
  unsigned int r = (u + 0x7FFFu + ((u >> 16) & 1u)) >> 16;  // RNE
  return (unsigned short)r;
}

__device__ __forceinline__ float bf2f(unsigned short s) {
  union { unsigned int u; float f; } v;
  v.u = ((unsigned int)s) << 16;
  return v.f;
}

// pack two f32 -> two bf16 (RNE) via scalar-cast path (compiler emits cvt_pk)
__device__ __forceinline__ unsigned int pk_bf16(float lo, float hi) {
  __hip_bfloat162 b = __float22bfloat162_rn(make_float2(lo, hi));
  union { __hip_bfloat162 b; unsigned int u; } c; c.b = b;
  return c.u;
}

#define LOG2E 1.4426950408889634f

// Prep (coalesced): blocks 0..63 transpose one 32-row slab of one head for
// BOTH weight matrices via an LDS tile (coalesced f32 reads, 16B bf16 writes).
// Blocks 64..71: params (sp8/sbi/sba), 2048 threads exactly.
__global__ __launch_bounds__(256) void prep_kernel(
    const float* __restrict__ w_in, const float* __restrict__ w_a,
    const float* __restrict__ a_param,
    const float* __restrict__ b_in, const float* __restrict__ b_a,
    unsigned short* __restrict__ wTin, unsigned short* __restrict__ wTa,
    float* __restrict__ sp8, float* __restrict__ sbi, float* __restrict__ sba) {
  const int b = blockIdx.x;
  if (b >= 64) {
    int tid = (b - 64) * 256 + threadIdx.x;   // 0..2047
    float v  = a_param[tid];
    float sp = (v > 20.0f) ? v : log1pf(__expf(v));
    sp8[tid] = 8.0f * sp * LOG2E;
    sbi[tid] = b_in[tid] * LOG2E;
    sba[tid] = b_a[tid] * LOG2E;
    return;
  }
  const int h  = b >> 2;
  const int i0 = (b & 3) * 32;                // input-dim slab
  __shared__ unsigned short tl[2][32][136];   // +8 pad

  const float* s0 = w_in + h * 16384 + i0 * 128;
  const float* s1 = w_a  + h * 16384 + i0 * 128;
#pragma unroll
  for (int it = 0; it < 4; ++it) {
    int e = it * 1024 + threadIdx.x * 4;      // 4 consecutive f32
    int r = e >> 7, c = e & 127;
    f32x4 v0 = *reinterpret_cast<const f32x4*>(s0 + r * 128 + c);
    f32x4 v1 = *reinterpret_cast<const f32x4*>(s1 + r * 128 + c);
#pragma unroll
    for (int k = 0; k < 4; ++k) {
      tl[0][r][c + k] = f2bf(v0[k] * LOG2E);
      tl[1][r][c + k] = f2bf(v1[k] * LOG2E);
    }
  }
  __syncthreads();

  const int j  = threadIdx.x >> 1;            // out col 0..127
  const int ih = (threadIdx.x & 1) * 16;      // i-half within slab
  u16x8 o0a, o0b, o1a, o1b;
#pragma unroll
  for (int k = 0; k < 8; ++k) {
    o0a[k] = tl[0][ih + k][j];      o0b[k] = tl[0][ih + 8 + k][j];
    o1a[k] = tl[1][ih + k][j];      o1b[k] = tl[1][ih + 8 + k][j];
  }
  unsigned short* d0 = wTin + h * 16384 + j * 128 + i0 + ih;
  unsigned short* d1 = wTa  + h * 16384 + j * 128 + i0 + ih;
  *reinterpret_cast<u16x8*>(d0)     = o0a;
  *reinterpret_cast<u16x8*>(d0 + 8) = o0b;
  *reinterpret_cast<u16x8*>(d1)     = o1a;
  *reinterpret_cast<u16x8*>(d1 + 8) = o1b;
}

// Main: R12/R17 structure — the measured optimum across 12 structural
// variants. Compact phases {stage -> barrier -> MFMA -> epilogue} preserve
// temporal access density (write-combining + LLC locality); log2-domain
// gates; bias folded into MFMA accumulator; XOR-swizzled LDS.
__global__ __launch_bounds__(256, 4) void rglru_kernel(
    const float* __restrict__ x, const float* __restrict__ state,
    const float* __restrict__ sbi, const float* __restrict__ sba,
    const unsigned short* __restrict__ wTin, const unsigned short* __restrict__ wTa,
    const float* __restrict__ sp8, float* __restrict__ out) {
  __shared__ unsigned short xs[BM * HDIM];  // bf16 x-tile, XOR-swizzled

  const int bid  = blockIdx.x;
  const int h    = bid & (NHEADS - 1);
  const int rb   = bid >> 4;
  const int t    = threadIdx.x;
  const int lane = t & 63;
  const int wid  = t >> 6;
  const int l15  = lane & 15;
  const int l4   = lane >> 4;

  // ---- stage x tile (BM x HDIM f32 -> bf16 LDS, swizzled); NT keeps x out
  // of LLC so state+out stay resident across replays ----
  const float* xtile = x + (long)rb * BM * WIDTH + h * HDIM;
#pragma unroll
  for (int it = 0; it < 8; ++it) {
    int idx = it * 256 + t;            // float4 index within tile (0..2047)
    int r   = idx >> 5;                // row 0..63
    int c4  = idx & 31;                // float4 within row
    f32x4 v = __builtin_nontemporal_load(
        reinterpret_cast<const f32x4*>(xtile + (long)r * WIDTH) + c4);
    uint2 p;
    p.x = pk_bf16(v[0], v[1]);
    p.y = pk_bf16(v[2], v[3]);
    int off = (r * 256 + c4 * 8) ^ ((r & 7) << 4);
    *reinterpret_cast<uint2*>(reinterpret_cast<char*>(xs) + off) = p;
  }

  // per-column constants (bias folded into acc init)
  const int cb = h * HDIM + wid * 32 + l4 * 4;
  f32x4 bi0 = *reinterpret_cast<const f32x4*>(sbi + cb);
  f32x4 bi1 = *reinterpret_cast<const f32x4*>(sbi + cb + 16);
  f32x4 ba0 = *reinterpret_cast<const f32x4*>(sba + cb);
  f32x4 ba1 = *reinterpret_cast<const f32x4*>(sba + cb + 16);
  f32x4 sp0 = *reinterpret_cast<const f32x4*>(sp8 + cb);
  f32x4 sp1 = *reinterpret_cast<const f32x4*>(sp8 + cb + 16);

  __syncthreads();

  // ---- MFMA: acc[m][n] initialized with bias (C-in accumulates) ----
  f32x4 acc_in[4][2], acc_a[4][2];
#pragma unroll
  for (int m = 0; m < 4; ++m) {
    acc_in[m][0] = bi0; acc_in[m][1] = bi1;
    acc_a[m][0]  = ba0; acc_a[m][1]  = ba1;
  }

  const unsigned short* wi0 = wTin + ((h * HDIM + wid * 32 + l15) * HDIM) + l4 * 8;
  const unsigned short* wi1 = wi0 + 16 * HDIM;
  const unsigned short* wa0 = wTa + ((h * HDIM + wid * 32 + l15) * HDIM) + l4 * 8;
  const unsigned short* wa1 = wa0 + 16 * HDIM;

  const int xsw = ((l15 & 7) << 4);   // per-thread swizzle bits (4..6)

#pragma unroll
  for (int kk = 0; kk < 4; ++kk) {
    bf16x8 xfr[4];
#pragma unroll
    for (int m = 0; m < 4; ++m) {
      int boff = ((m * 16 + l15) * 256 + kk * 64 + l4 * 16) ^ xsw;
      xfr[m] = *reinterpret_cast<const bf16x8*>(
          reinterpret_cast<const char*>(xs) + boff);
    }
    bf16x8 win[2], wa[2];
    win[0] = *reinterpret_cast<const bf16x8*>(wi0 + kk * 32);
    win[1] = *reinterpret_cast<const bf16x8*>(wi1 + kk * 32);
    wa[0]  = *reinterpret_cast<const bf16x8*>(wa0 + kk * 32);
    wa[1]  = *reinterpret_cast<const bf16x8*>(wa1 + kk * 32);
#pragma unroll
    for (int m = 0; m < 4; ++m)
#pragma unroll
      for (int n = 0; n < 2; ++n) {
        acc_in[m][n] = __builtin_amdgcn_mfma_f32_16x16x32_bf16(
            win[n], xfr[m], acc_in[m][n], 0, 0, 0);
        acc_a[m][n] = __builtin_amdgcn_mfma_f32_16x16x32_bf16(
            wa[n], xfr[m], acc_a[m][n], 0, 0, 0);
      }
  }

  // ---- epilogue ----
  const long base = (long)(rb * BM + l15) * WIDTH + cb;
  const float* ps = state + base;
  float*       po = out + base;
  const char* pxs = reinterpret_cast<const char*>(xs);
  // XOR applied after summing ALL low-order offsets (incl. n*32)
  const int xe0 = (l15 * 256 + (wid * 32 + l4 * 4) * 2) ^ xsw;        // n=0
  const int xe1 = (l15 * 256 + (wid * 32 + 16 + l4 * 4) * 2) ^ xsw;   // n=1

#pragma unroll
  for (int m = 0; m < 4; ++m) {
#pragma unroll
    for (int n = 0; n < 2; ++n) {
      f32x4 sv = *reinterpret_cast<const f32x4*>(ps + n * 16);
      u16x4 xb = *reinterpret_cast<const u16x4*>(
          pxs + (n ? xe1 : xe0) + m * 4096);
      f32x4 sp = n ? sp1 : sp0;
      f32x4 o;
#pragma unroll
      for (int r = 0; r < 4; ++r) {
        float gx  = __builtin_amdgcn_rcpf(1.0f + exp2f(-acc_in[m][n][r]));
        float ga  = __builtin_amdgcn_rcpf(1.0f + exp2f(-acc_a[m][n][r]));
        float av  = exp2f(-ga * sp[r]);
        float sc  = sqrtf(fmaxf(1.0f - av * av, 0.0f));
        o[r] = av * sv[r] + gx * bf2f(xb[r]) * sc;
      }
      *reinterpret_cast<f32x4*>(po + n * 16) = o;
    }
    ps += 16 * WIDTH;
    po += 16 * WIDTH;
  }
}

extern "C" void kernel_launch(void* const* d_in, const int* in_sizes, int n_in,
                              void* d_out, int out_size, void* d_ws, size_t ws_size,
                              hipStream_t stream) {
  const float* x       = (const float*)d_in[0];
  const float* state   = (const float*)d_in[1];
  const float* w_in    = (const float*)d_in[2];
  const float* b_in    = (const float*)d_in[3];
  const float* w_a     = (const float*)d_in[4];
  const float* b_a     = (const float*)d_in[5];
  const float* a_param = (const float*)d_in[6];
  float* out = (float*)d_out;

  unsigned short* wTin = (unsigned short*)d_ws;
  unsigned short* wTa  = wTin + NHEADS * HDIM * HDIM;
  float*          sp8  = (float*)(wTa + NHEADS * HDIM * HDIM);
  float*          sbi  = sp8 + WIDTH;
  float*          sba  = sbi + WIDTH;

  // prep: 64 transpose blocks (16 heads x 4 slabs) + 8 param blocks
  hipLaunchKernelGGL(prep_kernel, dim3(72), dim3(256), 0, stream,
                     w_in, w_a, a_param, b_in, b_a, wTin, wTa, sp8, sbi, sba);

  // main: 4096 blocks, 256 threads (R12/R17 structure)
  hipLaunchKernelGGL(rglru_kernel, dim3(4096), dim3(256), 0, stream,
                     x, state, sbi, sba, wTin, wTa, sp8, out);
}